// Round 1
// baseline (25777.686 us; speedup 1.0000x reference)
//
#include <hip/hip_runtime.h>
#include <math.h>

#define Bsz 256
#define Tsz 192
#define Fc 8
#define E0c 32
#define E1c 16
#define DIN 56
#define Hc 512
#define G4 2048  // 4*H

// ---------------- build x = concat(x_cont, emb0[cat0], emb1[cat1]) ----------------
__global__ void build_x_kernel(const float* __restrict__ x_cont,
                               const int* __restrict__ cat0,
                               const int* __restrict__ cat1,
                               const float* __restrict__ emb0,
                               const float* __restrict__ emb1,
                               float* __restrict__ x) {
    int idx = blockIdx.x * blockDim.x + threadIdx.x;
    int total = Bsz * Tsz * DIN;
    if (idx >= total) return;
    int d = idx % DIN;
    int bt = idx / DIN;
    float v;
    if (d < Fc)            v = x_cont[bt * Fc + d];
    else if (d < Fc + E0c) v = emb0[cat0[bt] * E0c + (d - Fc)];
    else                   v = emb1[cat1[bt] * E1c + (d - Fc - E0c)];
    x[idx] = v;
}

// ---------------- one LSTM timestep: z = A1@Wk + h_{t-1}@Wr + b; gates; c,h update --------
// Block computes a [32 batch x 16 h-col] tile, covering all 4 gates (64 z-cols).
// grid = (8, 32), block = 256.
__global__ __launch_bounds__(256) void lstm_step_kernel(
    const float* __restrict__ A1, int lda1, int K1,
    const float* __restrict__ Wk,
    const float* __restrict__ A2, int lda2,   // h_{t-1}, [B x H]; ignored when first_step
    const float* __restrict__ Wr,
    const float* __restrict__ bias,
    float* __restrict__ c_state,              // [B*H]
    float* __restrict__ h_out, int ldh,       // h_all + t*H, row stride T*H
    int first_step)
{
    __shared__ float As[32][8];
    __shared__ float Bs[8][64];
    int tid = threadIdx.x;
    int jj = tid & 15;       // h-column within tile
    int rp = tid >> 4;       // row pair 0..15
    int m0 = blockIdx.x * 32;
    int j0 = blockIdx.y * 16;

    float acc[2][4] = {{0.f,0.f,0.f,0.f},{0.f,0.f,0.f,0.f}};

    // phase 1: A1 @ Wk   (K1 is a multiple of 8: 56 or 512)
    for (int k0 = 0; k0 < K1; k0 += 8) {
        {
            int r = tid >> 3, k = tid & 7;
            As[r][k] = A1[(m0 + r) * lda1 + k0 + k];
        }
        {
            int i0 = tid, i1 = tid + 256;
            int kk0 = i0 >> 6, c0 = i0 & 63;
            int kk1 = i1 >> 6, c1 = i1 & 63;
            Bs[kk0][c0] = Wk[(k0 + kk0) * G4 + (c0 >> 4) * Hc + j0 + (c0 & 15)];
            Bs[kk1][c1] = Wk[(k0 + kk1) * G4 + (c1 >> 4) * Hc + j0 + (c1 & 15)];
        }
        __syncthreads();
        #pragma unroll
        for (int kk = 0; kk < 8; ++kk) {
            float a0 = As[2*rp][kk], a1 = As[2*rp+1][kk];
            float b0 = Bs[kk][jj], b1 = Bs[kk][16+jj], b2 = Bs[kk][32+jj], b3 = Bs[kk][48+jj];
            acc[0][0] += a0*b0; acc[0][1] += a0*b1; acc[0][2] += a0*b2; acc[0][3] += a0*b3;
            acc[1][0] += a1*b0; acc[1][1] += a1*b1; acc[1][2] += a1*b2; acc[1][3] += a1*b3;
        }
        __syncthreads();
    }

    // phase 2: h_{t-1} @ Wr (skip at t==0, h0 == 0)
    if (!first_step) {
        for (int k0 = 0; k0 < Hc; k0 += 8) {
            {
                int r = tid >> 3, k = tid & 7;
                As[r][k] = A2[(m0 + r) * lda2 + k0 + k];
            }
            {
                int i0 = tid, i1 = tid + 256;
                int kk0 = i0 >> 6, c0 = i0 & 63;
                int kk1 = i1 >> 6, c1 = i1 & 63;
                Bs[kk0][c0] = Wr[(k0 + kk0) * G4 + (c0 >> 4) * Hc + j0 + (c0 & 15)];
                Bs[kk1][c1] = Wr[(k0 + kk1) * G4 + (c1 >> 4) * Hc + j0 + (c1 & 15)];
            }
            __syncthreads();
            #pragma unroll
            for (int kk = 0; kk < 8; ++kk) {
                float a0 = As[2*rp][kk], a1 = As[2*rp+1][kk];
                float b0 = Bs[kk][jj], b1 = Bs[kk][16+jj], b2 = Bs[kk][32+jj], b3 = Bs[kk][48+jj];
                acc[0][0] += a0*b0; acc[0][1] += a0*b1; acc[0][2] += a0*b2; acc[0][3] += a0*b3;
                acc[1][0] += a1*b0; acc[1][1] += a1*b1; acc[1][2] += a1*b2; acc[1][3] += a1*b3;
            }
            __syncthreads();
        }
    }

    // gates: Keras order i, f, g, o
    int jg = j0 + jj;
    float bi = bias[jg], bf = bias[Hc + jg], bg = bias[2*Hc + jg], bo = bias[3*Hc + jg];
    #pragma unroll
    for (int r = 0; r < 2; ++r) {
        int b = m0 + 2*rp + r;
        float zi = acc[r][0] + bi;
        float zf = acc[r][1] + bf;
        float zg = acc[r][2] + bg;
        float zo = acc[r][3] + bo;
        float ig = 1.f / (1.f + expf(-zi));
        float fg = 1.f / (1.f + expf(-zf));
        float gg = tanhf(zg);
        float og = 1.f / (1.f + expf(-zo));
        float cprev = first_step ? 0.f : c_state[b * Hc + jg];
        float cn = fg * cprev + ig * gg;
        float hn = og * tanhf(cn);
        c_state[b * Hc + jg] = cn;
        h_out[b * ldh + jg] = hn;
    }
}

// ---------------- heads: mu = h@Wmu + bmu; sigma = softplus(h@Wsig + bsig) ----------------
__global__ __launch_bounds__(256) void head_kernel(
    const float* __restrict__ h2_all,
    const float* __restrict__ Wmu, const float* __restrict__ bmu,
    const float* __restrict__ Wsig, const float* __restrict__ bsig,
    float* __restrict__ out)
{
    int wid = threadIdx.x >> 6, lane = threadIdx.x & 63;
    int row = blockIdx.x * 4 + wid;  // row = b*T + t, < B*T
    const float* h = h2_all + (size_t)row * Hc;
    float smu = 0.f, ssg = 0.f;
    for (int e = lane; e < Hc; e += 64) {
        float hv = h[e];
        smu += hv * Wmu[e];
        ssg += hv * Wsig[e];
    }
    #pragma unroll
    for (int off = 32; off > 0; off >>= 1) {
        smu += __shfl_down(smu, off, 64);
        ssg += __shfl_down(ssg, off, 64);
    }
    if (lane == 0) {
        float mu = smu + bmu[0];
        float sg = ssg + bsig[0];
        float sp = sg > 0.f ? sg + log1pf(expf(-sg)) : log1pf(expf(sg));
        out[row] = mu;
        out[Bsz * Tsz + row] = sp;
    }
}

extern "C" void kernel_launch(void* const* d_in, const int* in_sizes, int n_in,
                              void* d_out, int out_size, void* d_ws, size_t ws_size,
                              hipStream_t stream) {
    const float* x_cont = (const float*)d_in[0];
    const int*   cat0   = (const int*)d_in[1];
    const int*   cat1   = (const int*)d_in[2];
    const float* emb0   = (const float*)d_in[3];
    const float* emb1   = (const float*)d_in[4];
    const float* Wk1    = (const float*)d_in[5];
    const float* Wr1    = (const float*)d_in[6];
    const float* b1     = (const float*)d_in[7];
    const float* Wk2    = (const float*)d_in[8];
    const float* Wr2    = (const float*)d_in[9];
    const float* b2     = (const float*)d_in[10];
    const float* Wmu    = (const float*)d_in[11];
    const float* bmu    = (const float*)d_in[12];
    const float* Wsig   = (const float*)d_in[13];
    const float* bsig   = (const float*)d_in[14];
    float* out = (float*)d_out;

    float* ws = (float*)d_ws;
    float* x  = ws;                               // B*T*DIN
    float* h1 = x  + (size_t)Bsz * Tsz * DIN;     // B*T*H
    float* h2 = h1 + (size_t)Bsz * Tsz * Hc;      // B*T*H
    float* c1 = h2 + (size_t)Bsz * Tsz * Hc;      // B*H
    float* c2 = c1 + (size_t)Bsz * Hc;            // B*H

    build_x_kernel<<<(Bsz * Tsz * DIN + 255) / 256, 256, 0, stream>>>(
        x_cont, cat0, cat1, emb0, emb1, x);

    dim3 grid(8, 32), block(256);
    for (int t = 0; t < Tsz; ++t) {
        lstm_step_kernel<<<grid, block, 0, stream>>>(
            x + (size_t)t * DIN, Tsz * DIN, DIN, Wk1,
            (t == 0) ? x : h1 + (size_t)(t - 1) * Hc, Tsz * Hc, Wr1,
            b1, c1, h1 + (size_t)t * Hc, Tsz * Hc, t == 0);
    }
    for (int t = 0; t < Tsz; ++t) {
        lstm_step_kernel<<<grid, block, 0, stream>>>(
            h1 + (size_t)t * Hc, Tsz * Hc, Hc, Wk2,
            (t == 0) ? x : h2 + (size_t)(t - 1) * Hc, Tsz * Hc, Wr2,
            b2, c2, h2 + (size_t)t * Hc, Tsz * Hc, t == 0);
    }
    head_kernel<<<(Bsz * Tsz) / 4, 256, 0, stream>>>(h2, Wmu, bmu, Wsig, bsig, out);
}

// Round 2
// 3950.154 us; speedup vs baseline: 6.5257x; 6.5257x over previous
//
#include <hip/hip_runtime.h>
#include <math.h>

#define Bsz 256
#define Tsz 192
#define Fc 8
#define E0c 32
#define E1c 16
#define Hc 512
#define G4 2048   // 4*H
#define DINP 64   // 56 padded to 64

typedef __attribute__((ext_vector_type(8))) short short8;
typedef __attribute__((ext_vector_type(4))) float f32x4;

static __device__ __forceinline__ float bf2f(ushort u) {
    return __uint_as_float(((uint)u) << 16);
}
static __device__ __forceinline__ ushort f2bf(float f) {
    uint u = __float_as_uint(f);
    u = (u + 0x7fffu + ((u >> 16) & 1u)) >> 16;
    return (ushort)u;
}

// ---------- build padded bf16 x, time-major [T][B][64] ----------
__global__ __launch_bounds__(256) void build_x_kernel(
    const float* __restrict__ x_cont, const int* __restrict__ cat0,
    const int* __restrict__ cat1, const float* __restrict__ emb0,
    const float* __restrict__ emb1, ushort* __restrict__ x_bf)
{
    int idx = blockIdx.x * 256 + threadIdx.x;          // over T*B*64
    if (idx >= Tsz * Bsz * DINP) return;
    int d = idx & 63;
    int row = idx >> 6;          // t*B + b
    int t = row >> 8;            // B = 256
    int b = row & 255;
    float v = 0.f;
    if (d < Fc)                 v = x_cont[(b * Tsz + t) * Fc + d];
    else if (d < Fc + E0c)      v = emb0[cat0[b * Tsz + t] * E0c + (d - Fc)];
    else if (d < Fc + E0c + E1c) v = emb1[cat1[b * Tsz + t] * E1c + (d - Fc - E0c)];
    x_bf[idx] = f2bf(v);
}

// ---------- transpose fp32 [K][2048] -> bf16 [2048][Kp] (zero-pad K..Kp) ----------
__global__ __launch_bounds__(256) void transpose_w_kernel(
    const float* __restrict__ in, ushort* __restrict__ out, int K, int Kp)
{
    __shared__ float tile[32][33];
    int k0 = blockIdx.x * 32;
    int n0 = blockIdx.y * 32;
    int tx = threadIdx.x & 31, ty = threadIdx.x >> 5;   // 32 x 8
    #pragma unroll
    for (int p = 0; p < 4; ++p) {
        int k = k0 + ty + p * 8;
        tile[ty + p * 8][tx] = (k < K) ? in[k * G4 + n0 + tx] : 0.f;
    }
    __syncthreads();
    #pragma unroll
    for (int p = 0; p < 4; ++p) {
        int nl = ty + p * 8;
        out[(size_t)(n0 + nl) * Kp + k0 + tx] = f2bf(tile[tx][nl]);
    }
}

// ---------- fused LSTM step: z = A_in@Wk^T + h_prev@Wr^T + b; gates; c,h ----------
// grid (8, 32), block 128 (2 waves). Block tile: 32 batch rows x 16 h-cols x 4 gates.
__global__ __launch_bounds__(128) void lstm_step_kernel(
    const ushort* __restrict__ A_in, int lda_in, int kin_tiles, // input activations
    const ushort* __restrict__ Wkt, int ldwk,                   // [2048][ldwk] bf16
    const ushort* __restrict__ h_prev,                          // [B][512] bf16
    const ushort* __restrict__ Wrt,                             // [2048][512] bf16
    const float* __restrict__ bias,
    float* __restrict__ c_state,                                // [B][512] fp32
    ushort* __restrict__ h_out,                                 // [B][512] bf16 (this t)
    int first_step)
{
    __shared__ ushort As[32][72];
    __shared__ ushort Bs[64][72];
    int tid = threadIdx.x;
    int w = tid >> 6, lane = tid & 63;
    int m0 = blockIdx.x * 32;
    int j0 = blockIdx.y * 16;

    // staging assignments
    int a_row = tid >> 2, a_koff = (tid & 3) * 16;   // 32 rows, 16 bf16 each
    int b_row = tid >> 1, b_koff = (tid & 1) * 32;   // 64 rows, 32 bf16 each
    int zcol = j0 + (b_row & 15) + (b_row >> 4) * Hc; // gate-interleaved W^T row

    f32x4 acc[4];
    #pragma unroll
    for (int g = 0; g < 4; ++g) acc[g] = (f32x4){0.f, 0.f, 0.f, 0.f};

    int ntot = kin_tiles + (first_step ? 0 : Hc / 64);

    uint4 ar0, ar1, br0, br1, br2, br3;
    auto load_tile = [&](int kt) {
        const ushort *ap, *bp;
        if (kt < kin_tiles) {
            ap = A_in + (size_t)(m0 + a_row) * lda_in + kt * 64 + a_koff;
            bp = Wkt + (size_t)zcol * ldwk + kt * 64 + b_koff;
        } else {
            int kr = kt - kin_tiles;
            ap = h_prev + (size_t)(m0 + a_row) * Hc + kr * 64 + a_koff;
            bp = Wrt + (size_t)zcol * Hc + kr * 64 + b_koff;
        }
        ar0 = *(const uint4*)ap;        ar1 = *(const uint4*)(ap + 8);
        br0 = *(const uint4*)bp;        br1 = *(const uint4*)(bp + 8);
        br2 = *(const uint4*)(bp + 16); br3 = *(const uint4*)(bp + 24);
    };

    load_tile(0);
    for (int kt = 0; kt < ntot; ++kt) {
        if (kt) __syncthreads();
        *(uint4*)&As[a_row][a_koff]     = ar0;
        *(uint4*)&As[a_row][a_koff + 8] = ar1;
        *(uint4*)&Bs[b_row][b_koff]      = br0;
        *(uint4*)&Bs[b_row][b_koff + 8]  = br1;
        *(uint4*)&Bs[b_row][b_koff + 16] = br2;
        *(uint4*)&Bs[b_row][b_koff + 24] = br3;
        __syncthreads();
        if (kt + 1 < ntot) load_tile(kt + 1);
        #pragma unroll
        for (int kk = 0; kk < 2; ++kk) {
            short8 af = *(const short8*)&As[w * 16 + (lane & 15)][kk * 32 + (lane >> 4) * 8];
            #pragma unroll
            for (int nf = 0; nf < 4; ++nf) {
                short8 bfr = *(const short8*)&Bs[nf * 16 + (lane & 15)][kk * 32 + (lane >> 4) * 8];
                acc[nf] = __builtin_amdgcn_mfma_f32_16x16x32_bf16(af, bfr, acc[nf], 0, 0, 0);
            }
        }
    }

    // epilogue: lane owns rows m0 + w*16 + quad*4 + r (r=0..3), h-col j0 + (lane&15)
    int j = j0 + (lane & 15);
    float bi = bias[j], bff = bias[Hc + j], bg = bias[2 * Hc + j], bo = bias[3 * Hc + j];
    int quad = lane >> 4;
    #pragma unroll
    for (int r = 0; r < 4; ++r) {
        int row = m0 + w * 16 + quad * 4 + r;     // batch index b
        float zi = acc[0][r] + bi;
        float zf = acc[1][r] + bff;
        float zg = acc[2][r] + bg;
        float zo = acc[3][r] + bo;
        float ig = 1.f / (1.f + __expf(-zi));
        float fg = 1.f / (1.f + __expf(-zf));
        float gg = tanhf(zg);
        float og = 1.f / (1.f + __expf(-zo));
        size_t cidx = (size_t)row * Hc + j;
        float cprev = first_step ? 0.f : c_state[cidx];
        float cn = fg * cprev + ig * gg;
        float hn = og * tanhf(cn);
        c_state[cidx] = cn;
        h_out[cidx] = f2bf(hn);
    }
}

// ---------- heads ----------
__global__ __launch_bounds__(256) void head_kernel(
    const ushort* __restrict__ h2_all,   // [T][B][512] bf16
    const float* __restrict__ Wmu, const float* __restrict__ bmu,
    const float* __restrict__ Wsig, const float* __restrict__ bsig,
    float* __restrict__ out)
{
    int wid = threadIdx.x >> 6, lane = threadIdx.x & 63;
    int row_tm = blockIdx.x * 4 + wid;           // t*B + b
    const ushort* h = h2_all + (size_t)row_tm * Hc;
    float smu = 0.f, ssg = 0.f;
    for (int e = lane; e < Hc; e += 64) {
        float hv = bf2f(h[e]);
        smu += hv * Wmu[e];
        ssg += hv * Wsig[e];
    }
    #pragma unroll
    for (int off = 32; off > 0; off >>= 1) {
        smu += __shfl_down(smu, off, 64);
        ssg += __shfl_down(ssg, off, 64);
    }
    if (lane == 0) {
        int t = row_tm >> 8, b = row_tm & 255;
        int oi = b * Tsz + t;
        float mu = smu + bmu[0];
        float sg = ssg + bsig[0];
        float sp = sg > 0.f ? sg + log1pf(__expf(-sg)) : log1pf(__expf(sg));
        out[oi] = mu;
        out[Bsz * Tsz + oi] = sp;
    }
}

extern "C" void kernel_launch(void* const* d_in, const int* in_sizes, int n_in,
                              void* d_out, int out_size, void* d_ws, size_t ws_size,
                              hipStream_t stream) {
    const float* x_cont = (const float*)d_in[0];
    const int*   cat0   = (const int*)d_in[1];
    const int*   cat1   = (const int*)d_in[2];
    const float* emb0   = (const float*)d_in[3];
    const float* emb1   = (const float*)d_in[4];
    const float* Wk1    = (const float*)d_in[5];
    const float* Wr1    = (const float*)d_in[6];
    const float* b1     = (const float*)d_in[7];
    const float* Wk2    = (const float*)d_in[8];
    const float* Wr2    = (const float*)d_in[9];
    const float* b2     = (const float*)d_in[10];
    const float* Wmu    = (const float*)d_in[11];
    const float* bmu    = (const float*)d_in[12];
    const float* Wsig   = (const float*)d_in[13];
    const float* bsig   = (const float*)d_in[14];
    float* out = (float*)d_out;

    char* ws = (char*)d_ws;
    ushort* x_bf  = (ushort*)ws;                                  ws += (size_t)Tsz * Bsz * DINP * 2;
    ushort* Wkt1  = (ushort*)ws;                                  ws += (size_t)G4 * DINP * 2;
    ushort* Wrt1  = (ushort*)ws;                                  ws += (size_t)G4 * Hc * 2;
    ushort* Wkt2  = (ushort*)ws;                                  ws += (size_t)G4 * Hc * 2;
    ushort* Wrt2  = (ushort*)ws;                                  ws += (size_t)G4 * Hc * 2;
    ushort* h1    = (ushort*)ws;                                  ws += (size_t)Tsz * Bsz * Hc * 2;
    ushort* h2    = (ushort*)ws;                                  ws += (size_t)Tsz * Bsz * Hc * 2;
    float*  c1    = (float*)ws;                                   ws += (size_t)Bsz * Hc * 4;
    float*  c2    = (float*)ws;

    build_x_kernel<<<(Tsz * Bsz * DINP + 255) / 256, 256, 0, stream>>>(
        x_cont, cat0, cat1, emb0, emb1, x_bf);
    transpose_w_kernel<<<dim3(DINP / 32, G4 / 32), 256, 0, stream>>>(Wk1, Wkt1, 56, DINP);
    transpose_w_kernel<<<dim3(Hc / 32, G4 / 32), 256, 0, stream>>>(Wr1, Wrt1, Hc, Hc);
    transpose_w_kernel<<<dim3(Hc / 32, G4 / 32), 256, 0, stream>>>(Wk2, Wkt2, Hc, Hc);
    transpose_w_kernel<<<dim3(Hc / 32, G4 / 32), 256, 0, stream>>>(Wr2, Wrt2, Hc, Hc);

    dim3 grid(Bsz / 32, Hc / 16), block(128);
    for (int t = 0; t < Tsz; ++t) {
        lstm_step_kernel<<<grid, block, 0, stream>>>(
            x_bf + (size_t)t * Bsz * DINP, DINP, DINP / 64, Wkt1, DINP,
            h1 + (size_t)(t - 1) * Bsz * Hc, Wrt1, b1, c1,
            h1 + (size_t)t * Bsz * Hc, t == 0);
    }
    for (int t = 0; t < Tsz; ++t) {
        lstm_step_kernel<<<grid, block, 0, stream>>>(
            h1 + (size_t)t * Bsz * Hc, Hc, Hc / 64, Wkt2, Hc,
            h2 + (size_t)(t - 1) * Bsz * Hc, Wrt2, b2, c2,
            h2 + (size_t)t * Bsz * Hc, t == 0);
    }
    head_kernel<<<(Bsz * Tsz) / 4, 256, 0, stream>>>(h2, Wmu, bmu, Wsig, bsig, out);
}